// Round 14
// baseline (363.466 us; speedup 1.0000x reference)
//
#include <hip/hip_runtime.h>
#include <stdint.h>

typedef __bf16 bf16_t;
typedef bf16_t bf16x8 __attribute__((ext_vector_type(8)));
typedef float f32x4 __attribute__((ext_vector_type(4)));
typedef unsigned short u16x8 __attribute__((ext_vector_type(8)));

#define KDIM 512

__device__ __forceinline__ unsigned short f2bf(float f) {
  unsigned int u = __float_as_uint(f);
  u = (u + 0x7FFFu + ((u >> 16) & 1u)) >> 16;
  return (unsigned short)u;
}

// ================= merged prep: bias | transpose+cvt | fp32->bf16 cvt =========================
// grid 8624: [0,48) bias fuse; [48,3120) transpose W -> WtB; [3120,8624) cvt xs+Wp.
struct PrepArgs {
  const float *s0, *s1, *s2, *s3, *s4;
  unsigned short *d0, *d1, *d2, *d3, *d4;
  const float *w0, *w1, *w2, *w3;
  unsigned short *t0, *t1, *t2, *t3;
  const float *b0, *b1, *b2, *b3;
  const float *Wp, *bp;
  float *bf;
};
__device__ __forceinline__ void cvt8(const float* s, unsigned short* d, int i) {
  const float4* sp = (const float4*)s;
  float4 a = sp[2 * (size_t)i], b = sp[2 * (size_t)i + 1];
  u16x8 r;
  r[0] = f2bf(a.x); r[1] = f2bf(a.y); r[2] = f2bf(a.z); r[3] = f2bf(a.w);
  r[4] = f2bf(b.x); r[5] = f2bf(b.y); r[6] = f2bf(b.z); r[7] = f2bf(b.w);
  *(u16x8*)(d + (size_t)8 * i) = r;
}
__global__ __launch_bounds__(256) void prep_all(PrepArgs a) {
  __shared__ float tile[64][65];
  int bid = blockIdx.x;
  int t = threadIdx.x;
  if (bid < 48) {  // ---- bias fuse (float4 loads, 4-wide acc) ----
    int jg = bid;
    int e, base;
    if (jg < 4)       { e = 0; base = 0; }
    else if (jg < 12) { e = 1; base = 4; }
    else if (jg < 24) { e = 2; base = 12; }
    else              { e = 3; base = 24; }
    const float* b = e == 0 ? a.b0 : e == 1 ? a.b1 : e == 2 ? a.b2 : a.b3;
    int jl = jg - base;
    const float4* br4 = (const float4*)(b + (size_t)jl * 512);
#pragma unroll
    for (int oo = 0; oo < 2; ++oo) {
      int o = t + oo * 256;
      const float4* wr4 = (const float4*)(a.Wp + (size_t)o * 512);
      float sx = 0.f, sy = 0.f, sz = 0.f, sw = 0.f;
#pragma unroll 4
      for (int i = 0; i < 128; ++i) {
        float4 wv = wr4[i], bv = br4[i];
        sx += wv.x * bv.x; sy += wv.y * bv.y; sz += wv.z * bv.z; sw += wv.w * bv.w;
      }
      a.bf[(size_t)jg * 512 + o] = a.bp[o] + ((sx + sy) + (sz + sw));
    }
  } else if (bid < 3120) {  // ---- transpose+cvt: float4 loads, ushort8 stores ----
    int r = bid - 48;
    int e, base, P;
    if (r < 256)       { e = 0; base = 0;    P = 4; }
    else if (r < 768)  { e = 1; base = 256;  P = 8; }
    else if (r < 1536) { e = 2; base = 768;  P = 12; }
    else               { e = 3; base = 1536; P = 24; }
    const float* W = e == 0 ? a.w0 : e == 1 ? a.w1 : e == 2 ? a.w2 : a.w3;
    unsigned short* Wt = e == 0 ? a.t0 : e == 1 ? a.t1 : e == 2 ? a.t2 : a.t3;
    r -= base;
    int qb = r % (P * 8), db = r / (P * 8);
    int q0 = qb * 64, d0 = db * 64;
    int c4 = t & 15, rgrp = t >> 4;
#pragma unroll
    for (int i = 0; i < 4; ++i) {
      int row = rgrp + i * 16;
      float4 v = *(const float4*)&W[(size_t)(q0 + row) * 512 + d0 + c4 * 4];
      tile[row][c4 * 4 + 0] = v.x; tile[row][c4 * 4 + 1] = v.y;
      tile[row][c4 * 4 + 2] = v.z; tile[row][c4 * 4 + 3] = v.w;
    }
    __syncthreads();
    int j = q0 >> 9, e0 = q0 & 511;
    size_t obase = (size_t)j * 262144 + (size_t)d0 * 512 + e0;
#pragma unroll
    for (int it = 0; it < 2; ++it) {
      int pair = it * 256 + t;
      int dd = pair >> 3, ch = pair & 7;
      u16x8 o8;
#pragma unroll
      for (int k = 0; k < 8; ++k) o8[k] = f2bf(tile[ch * 8 + k][dd]);
      *(u16x8*)&Wt[obase + (size_t)dd * 512 + ch * 8] = o8;
    }
  } else {  // ---- fp32->bf16 cvt ----
    int i = (bid - 3120) * 256 + t;
    if (i < 688128)       cvt8(a.s0, a.d0, i);
    else if (i < 1032192) cvt8(a.s1, a.d1, i - 688128);
    else if (i < 1261568) cvt8(a.s2, a.d2, i - 1032192);
    else if (i < 1376256) cvt8(a.s3, a.d3, i - 1261568);
    else                  cvt8(a.s4, a.d4, i - 1376256);
  }
}

// ================= async global->LDS helpers ==================================================
__device__ __forceinline__ void gload_lds16(const unsigned short* g, unsigned short* l) {
  __builtin_amdgcn_global_load_lds(
      (const __attribute__((address_space(1))) void*)g,
      (__attribute__((address_space(3))) void*)l, 16, 0, 0);
}

// ---- stage a 128x32 bf16 tile (8 KB): LDS dest linear, global source chunk-swizzled ----
__device__ __forceinline__ void stage32(const unsigned short* __restrict__ g,
                                        char* ldsOp, int tid, int kt) {
  int rlo = tid >> 2;
  int c = (tid & 3) ^ ((tid >> 3) & 3);
#pragma unroll
  for (int i = 0; i < 2; ++i) {
    int row = i * 64 + rlo;
    gload_lds16(g + (size_t)row * KDIM + kt * 32 + c * 8,
                (unsigned short*)(ldsOp + i * 4096 + tid * 16));
  }
}
__device__ __forceinline__ bf16x8 lds_frag32(const char* op, int r, int c16) {
  return *(const bf16x8*)(op + r * 64 + ((c16 ^ ((r >> 1) & 3)) << 4));
}

// ================= 128x128 bf16 MFMA core, BK=32, 3-slot ring, counted vmcnt ==================
// (unchanged from R7 — proven structure; first asm "memory" also pins any pre-issued loads)
__device__ __forceinline__ void gemm128_k512(
    const unsigned short* __restrict__ Ag, const unsigned short* __restrict__ Bg,
    char* lds, int tid, f32x4 acc[4][4]) {
  int lane = tid & 63, w = tid >> 6;
  int wr0 = (w >> 1) * 64, wc0 = (w & 1) * 64;
  int c16 = lane >> 4, rl = lane & 15;
  stage32(Ag, lds, tid, 0);
  stage32(Bg, lds + 8192, tid, 0);
  stage32(Ag, lds + 16384, tid, 1);
  stage32(Bg, lds + 16384 + 8192, tid, 1);
#pragma unroll
  for (int s = 0; s < 16; ++s) {
    if (s < 15) asm volatile("s_waitcnt vmcnt(4)\n\ts_barrier" ::: "memory");
    else        asm volatile("s_waitcnt vmcnt(0)\n\ts_barrier" ::: "memory");
    char* cur = lds + (s % 3) * 16384;
    if (s + 2 < 16) {
      char* nxt = lds + ((s + 2) % 3) * 16384;
      stage32(Ag, nxt, tid, s + 2);
      stage32(Bg, nxt + 8192, tid, s + 2);
    }
    bf16x8 av[4], bv[4];
#pragma unroll
    for (int f = 0; f < 4; ++f) {
      av[f] = lds_frag32(cur, wr0 + f * 16 + rl, c16);
      bv[f] = lds_frag32(cur + 8192, wc0 + f * 16 + rl, c16);
    }
    __builtin_amdgcn_s_setprio(1);
#pragma unroll
    for (int fi = 0; fi < 4; ++fi)
#pragma unroll
      for (int fj = 0; fj < 4; ++fj)
        acc[fi][fj] = __builtin_amdgcn_mfma_f32_16x16x32_bf16(av[fi], bv[fj], acc[fi][fj], 0, 0, 0);
    __builtin_amdgcn_s_setprio(0);
  }
}

// ================= merged weight-fuse GEMM ====================================================
struct FuseArgs {
  const unsigned short *wt0, *wt1, *wt2, *wt3;
  unsigned short *wf0, *wf1, *wf2, *wf3;
};
__global__ __launch_bounds__(256, 3) void fuse_all(const unsigned short* __restrict__ Wpb, FuseArgs a) {
  __shared__ __align__(16) char lds[49152];
  int bid = blockIdx.x;
  int e, base, P;
  if (bid < 64)       { e = 0; base = 0;   P = 4; }
  else if (bid < 192) { e = 1; base = 64;  P = 8; }
  else if (bid < 384) { e = 2; base = 192; P = 12; }
  else                { e = 3; base = 384; P = 24; }
  const unsigned short* WtB = e == 0 ? a.wt0 : e == 1 ? a.wt1 : e == 2 ? a.wt2 : a.wt3;
  unsigned short* Wf = e == 0 ? a.wf0 : e == 1 ? a.wf1 : e == 2 ? a.wf2 : a.wf3;
  int r = bid - base;
  int tileM = r % (4 * P), tileN = r / (4 * P);
  int tid = threadIdx.x;
  int lane = tid & 63, w = tid >> 6;
  int wr0 = (w >> 1) * 64, wc0 = (w & 1) * 64;
  int j = (tileM * 128) >> 9;
  const unsigned short* Ag = Wpb + (size_t)((tileM * 128) & 511) * 512;
  const unsigned short* Bg = WtB + (size_t)j * 262144 + (size_t)(tileN * 128) * 512;
  f32x4 acc[4][4] = {};
  gemm128_k512(Ag, Bg, lds, tid, acc);
#pragma unroll
  for (int fi = 0; fi < 4; ++fi)
#pragma unroll
    for (int fj = 0; fj < 4; ++fj) {
      int col = tileN * 128 + wc0 + fj * 16 + (lane & 15);
#pragma unroll
      for (int r2 = 0; r2 < 4; ++r2) {
        int m = tileM * 128 + wr0 + fi * 16 + (lane >> 4) * 4 + r2;
        Wf[(size_t)m * 512 + col] = f2bf(acc[fi][fj][r2]);
      }
    }
}

// ================= fused expert GEMM + gate + scatter (STORE / ADD kernels) ===================
// Routing: E0+E2 disjoint rows -> STORE kernel; E1+E3 disjoint rows -> ADD kernel (pure RMW).
// Stream order gives all deps.  2D XCD chunking <XM,XN>: xcd owns TM/XM x TN/XN tiles ->
// per-XCD panels fit 4MB L2 (E0/E1: 3.6MB, E2/E3: 3.25MB).  Output traffic uses non-temporal
// hints so the 176MB streams don't evict the operand panels.  ADD prefetches all 64 RMW values
// as nt-loads BEFORE the K-loop (the core's first asm "memory" pins them in the prologue).
template <int L, int P, int EXPERT, int XM, int XN, bool STORE>
__device__ __forceinline__ void expert_body(
    const unsigned short* __restrict__ A, const unsigned short* __restrict__ Wf,
    const float* __restrict__ bf, const float* __restrict__ gates,
    const int* __restrict__ bidx, float* __restrict__ out, char* lds, int bid, int tid) {
  constexpr int TM = L;
  constexpr int TN = 4 * P;
  constexpr int TMl = TM / XM, TNl = TN / XN;  // all divisible by construction
  constexpr int EBASE = 128 * EXPERT;
  int xcd = bid & 7, pos = bid >> 3;
  int tileM = (xcd / XN) * TMl + pos / TNl;
  int tileN = (xcd % XN) * TNl + pos % TNl;

  int lane = tid & 63, w = tid >> 6;
  int wr0 = (w >> 1) * 64, wc0 = (w & 1) * 64;
  const unsigned short* Ag = A + (size_t)tileM * 128 * KDIM;
  const unsigned short* Bg = Wf + (size_t)tileN * 128 * KDIM;

  int j = tileN >> 2;
  int obase = (tileN & 3) * 128;
  int ocol[4];
#pragma unroll
  for (int fj = 0; fj < 4; ++fj) ocol[fj] = obase + wc0 + fj * 16 + (lane & 15);

  // ---- RMW prefetch (ADD only): 64 nt-loads issued before the K-loop ----
  float old[4][4][4];
  if (!STORE) {
#pragma unroll
    for (int fi = 0; fi < 4; ++fi) {
      int m0 = tileM * 128 + wr0 + fi * 16 + (lane >> 4) * 4;
      int n = m0 / L, li = m0 - n * L;
#pragma unroll
      for (int r = 0; r < 4; ++r) {
        if (li == L) { li = 0; ++n; }
        int b = bidx[EBASE + n];
        const float* rp = out + ((size_t)b * 336 + li * P + j) * 512;
#pragma unroll
        for (int fj = 0; fj < 4; ++fj)
          old[fi][r][fj] = __builtin_nontemporal_load(rp + ocol[fj]);
        ++li;
      }
    }
  }

  f32x4 acc[4][4] = {};
  gemm128_k512(Ag, Bg, lds, tid, acc);

  float bv[4];
#pragma unroll
  for (int fj = 0; fj < 4; ++fj) bv[fj] = bf[(j << 9) + ocol[fj]];
#pragma unroll
  for (int fi = 0; fi < 4; ++fi) {
    int m0 = tileM * 128 + wr0 + fi * 16 + (lane >> 4) * 4;
    int n = m0 / L, li = m0 - n * L;
#pragma unroll
    for (int r = 0; r < 4; ++r) {
      if (li == L) { li = 0; ++n; }
      int b = bidx[EBASE + n];
      float g = gates[b * 4 + EXPERT];
      float* rp = out + ((size_t)b * 336 + li * P + j) * 512;
#pragma unroll
      for (int fj = 0; fj < 4; ++fj) {
        float v = g * (acc[fi][fj][r] + bv[fj]);
        if (!STORE) v += old[fi][r][fj];
        __builtin_nontemporal_store(v, rp + ocol[fj]);
      }
      ++li;
    }
  }
}

struct ScatterArgs {
  const unsigned short *xa, *wa;
  const unsigned short *xb, *wb;
  const float *bfa, *bfb;
  const float *gates;
  const int *bidx;
  float *out;
};

// STORE kernel: E0 (bid<1344) + E2 (bid>=1344) — disjoint output rows, pure stores.
__global__ __launch_bounds__(256, 3) void scatter_store(ScatterArgs a) {
  __shared__ __align__(16) char lds[49152];
  int tid = threadIdx.x;
  if (blockIdx.x < 1344)
    expert_body<84, 4, 0, 4, 2, true>(a.xa, a.wa, a.bfa, a.gates, a.bidx, a.out, lds, blockIdx.x, tid);
  else
    expert_body<28, 12, 2, 2, 4, true>(a.xb, a.wb, a.bfb, a.gates, a.bidx, a.out, lds, blockIdx.x - 1344, tid);
}

// ADD kernel: E1 (bid<1344) + E3 (bid>=1344) — disjoint output rows, pure RMW.
__global__ __launch_bounds__(256, 3) void scatter_add(ScatterArgs a) {
  __shared__ __align__(16) char lds[49152];
  int tid = threadIdx.x;
  if (blockIdx.x < 1344)
    expert_body<42, 8, 1, 2, 4, false>(a.xa, a.wa, a.bfa, a.gates, a.bidx, a.out, lds, blockIdx.x, tid);
  else
    expert_body<14, 24, 3, 1, 8, false>(a.xb, a.wb, a.bfb, a.gates, a.bidx, a.out, lds, blockIdx.x - 1344, tid);
}

extern "C" void kernel_launch(void* const* d_in, const int* in_sizes, int n_in,
                              void* d_out, int out_size, void* d_ws, size_t ws_size,
                              hipStream_t stream) {
  const float* xs[4]   = {(const float*)d_in[0], (const float*)d_in[3], (const float*)d_in[6], (const float*)d_in[9]};
  const float* Wfp[4]  = {(const float*)d_in[1], (const float*)d_in[4], (const float*)d_in[7], (const float*)d_in[10]};
  const float* bias[4] = {(const float*)d_in[2], (const float*)d_in[5], (const float*)d_in[8], (const float*)d_in[11]};
  const float* gates = (const float*)d_in[12];
  const float* Wp    = (const float*)d_in[13];
  const float* bp    = (const float*)d_in[14];
  const int* bidx    = (const int*)d_in[15];

  static const int xs_elems[4] = {5505024, 2752512, 1835008, 917504};
  static const int W_elems[4]  = {1048576, 2097152, 3145728, 6291456};

  unsigned short* w = (unsigned short*)d_ws;
  size_t off = 0;
  unsigned short* xsb[4]; unsigned short* WtB[4]; unsigned short* Wfb[4];
  for (int i = 0; i < 4; i++) { xsb[i] = w + off; off += xs_elems[i]; }
  for (int i = 0; i < 4; i++) { WtB[i] = w + off; off += W_elems[i]; }
  for (int i = 0; i < 4; i++) { Wfb[i] = w + off; off += W_elems[i]; }
  unsigned short* Wpb = w + off; off += 262144;
  float* bfused = (float*)(w + off);  // 48*512 floats

  // --- prep: ONE launch (bias | transpose | cvt) ---
  PrepArgs pa;
  pa.s0 = xs[0]; pa.s1 = xs[1]; pa.s2 = xs[2]; pa.s3 = xs[3]; pa.s4 = Wp;
  pa.d0 = xsb[0]; pa.d1 = xsb[1]; pa.d2 = xsb[2]; pa.d3 = xsb[3]; pa.d4 = Wpb;
  pa.w0 = Wfp[0]; pa.w1 = Wfp[1]; pa.w2 = Wfp[2]; pa.w3 = Wfp[3];
  pa.t0 = WtB[0]; pa.t1 = WtB[1]; pa.t2 = WtB[2]; pa.t3 = WtB[3];
  pa.b0 = bias[0]; pa.b1 = bias[1]; pa.b2 = bias[2]; pa.b3 = bias[3];
  pa.Wp = Wp; pa.bp = bp; pa.bf = bfused;
  prep_all<<<8624, 256, 0, stream>>>(pa);

  // --- weight fuse GEMM ---
  FuseArgs fa = {WtB[0], WtB[1], WtB[2], WtB[3], Wfb[0], Wfb[1], Wfb[2], Wfb[3]};
  fuse_all<<<768, 256, 0, stream>>>(Wpb, fa);

  // --- expert GEMM + gated scatter: STORE (E0+E2) then ADD (E1+E3) ---
  ScatterArgs sa;
  sa.gates = gates; sa.bidx = bidx; sa.out = (float*)d_out;
  sa.xa = xsb[0]; sa.wa = Wfb[0]; sa.bfa = bfused + 0 * 512;
  sa.xb = xsb[2]; sa.wb = Wfb[2]; sa.bfb = bfused + 12 * 512;
  scatter_store<<<2688, 256, 0, stream>>>(sa);

  sa.xa = xsb[1]; sa.wa = Wfb[1]; sa.bfa = bfused + 4 * 512;
  sa.xb = xsb[3]; sa.wb = Wfb[3]; sa.bfb = bfused + 24 * 512;
  scatter_add<<<2688, 256, 0, stream>>>(sa);
}

// Round 15
// 251.354 us; speedup vs baseline: 1.4460x; 1.4460x over previous
//
#include <hip/hip_runtime.h>
#include <stdint.h>

typedef __bf16 bf16_t;
typedef bf16_t bf16x8 __attribute__((ext_vector_type(8)));
typedef float f32x4 __attribute__((ext_vector_type(4)));
typedef unsigned short u16x8 __attribute__((ext_vector_type(8)));

#define KDIM 512

__device__ __forceinline__ unsigned short f2bf(float f) {
  unsigned int u = __float_as_uint(f);
  u = (u + 0x7FFFu + ((u >> 16) & 1u)) >> 16;
  return (unsigned short)u;
}

// ================= merged prep: bias | transpose+cvt | fp32->bf16 cvt =========================
// grid 8624: [0,48) bias fuse; [48,3120) transpose W -> WtB; [3120,8624) cvt xs+Wp.
struct PrepArgs {
  const float *s0, *s1, *s2, *s3, *s4;
  unsigned short *d0, *d1, *d2, *d3, *d4;
  const float *w0, *w1, *w2, *w3;
  unsigned short *t0, *t1, *t2, *t3;
  const float *b0, *b1, *b2, *b3;
  const float *Wp, *bp;
  float *bf;
};
__device__ __forceinline__ void cvt8(const float* s, unsigned short* d, int i) {
  const float4* sp = (const float4*)s;
  float4 a = sp[2 * (size_t)i], b = sp[2 * (size_t)i + 1];
  u16x8 r;
  r[0] = f2bf(a.x); r[1] = f2bf(a.y); r[2] = f2bf(a.z); r[3] = f2bf(a.w);
  r[4] = f2bf(b.x); r[5] = f2bf(b.y); r[6] = f2bf(b.z); r[7] = f2bf(b.w);
  *(u16x8*)(d + (size_t)8 * i) = r;
}
__global__ __launch_bounds__(256) void prep_all(PrepArgs a) {
  __shared__ float tile[64][65];
  int bid = blockIdx.x;
  int t = threadIdx.x;
  if (bid < 48) {  // ---- bias fuse (float4 loads, 4-wide acc) ----
    int jg = bid;
    int e, base;
    if (jg < 4)       { e = 0; base = 0; }
    else if (jg < 12) { e = 1; base = 4; }
    else if (jg < 24) { e = 2; base = 12; }
    else              { e = 3; base = 24; }
    const float* b = e == 0 ? a.b0 : e == 1 ? a.b1 : e == 2 ? a.b2 : a.b3;
    int jl = jg - base;
    const float4* br4 = (const float4*)(b + (size_t)jl * 512);
#pragma unroll
    for (int oo = 0; oo < 2; ++oo) {
      int o = t + oo * 256;
      const float4* wr4 = (const float4*)(a.Wp + (size_t)o * 512);
      float sx = 0.f, sy = 0.f, sz = 0.f, sw = 0.f;
#pragma unroll 4
      for (int i = 0; i < 128; ++i) {
        float4 wv = wr4[i], bv = br4[i];
        sx += wv.x * bv.x; sy += wv.y * bv.y; sz += wv.z * bv.z; sw += wv.w * bv.w;
      }
      a.bf[(size_t)jg * 512 + o] = a.bp[o] + ((sx + sy) + (sz + sw));
    }
  } else if (bid < 3120) {  // ---- transpose+cvt: float4 loads, ushort8 stores ----
    int r = bid - 48;
    int e, base, P;
    if (r < 256)       { e = 0; base = 0;    P = 4; }
    else if (r < 768)  { e = 1; base = 256;  P = 8; }
    else if (r < 1536) { e = 2; base = 768;  P = 12; }
    else               { e = 3; base = 1536; P = 24; }
    const float* W = e == 0 ? a.w0 : e == 1 ? a.w1 : e == 2 ? a.w2 : a.w3;
    unsigned short* Wt = e == 0 ? a.t0 : e == 1 ? a.t1 : e == 2 ? a.t2 : a.t3;
    r -= base;
    int qb = r % (P * 8), db = r / (P * 8);
    int q0 = qb * 64, d0 = db * 64;
    int c4 = t & 15, rgrp = t >> 4;
#pragma unroll
    for (int i = 0; i < 4; ++i) {
      int row = rgrp + i * 16;
      float4 v = *(const float4*)&W[(size_t)(q0 + row) * 512 + d0 + c4 * 4];
      tile[row][c4 * 4 + 0] = v.x; tile[row][c4 * 4 + 1] = v.y;
      tile[row][c4 * 4 + 2] = v.z; tile[row][c4 * 4 + 3] = v.w;
    }
    __syncthreads();
    int j = q0 >> 9, e0 = q0 & 511;
    size_t obase = (size_t)j * 262144 + (size_t)d0 * 512 + e0;
#pragma unroll
    for (int it = 0; it < 2; ++it) {
      int pair = it * 256 + t;
      int dd = pair >> 3, ch = pair & 7;
      u16x8 o8;
#pragma unroll
      for (int k = 0; k < 8; ++k) o8[k] = f2bf(tile[ch * 8 + k][dd]);
      *(u16x8*)&Wt[obase + (size_t)dd * 512 + ch * 8] = o8;
    }
  } else {  // ---- fp32->bf16 cvt ----
    int i = (bid - 3120) * 256 + t;
    if (i < 688128)       cvt8(a.s0, a.d0, i);
    else if (i < 1032192) cvt8(a.s1, a.d1, i - 688128);
    else if (i < 1261568) cvt8(a.s2, a.d2, i - 1032192);
    else if (i < 1376256) cvt8(a.s3, a.d3, i - 1261568);
    else                  cvt8(a.s4, a.d4, i - 1376256);
  }
}

// ================= async global->LDS helpers ==================================================
__device__ __forceinline__ void gload_lds16(const unsigned short* g, unsigned short* l) {
  __builtin_amdgcn_global_load_lds(
      (const __attribute__((address_space(1))) void*)g,
      (__attribute__((address_space(3))) void*)l, 16, 0, 0);
}

// ---- stage a 128x32 bf16 tile (8 KB): LDS dest linear, global source chunk-swizzled ----
__device__ __forceinline__ void stage32(const unsigned short* __restrict__ g,
                                        char* ldsOp, int tid, int kt) {
  int rlo = tid >> 2;
  int c = (tid & 3) ^ ((tid >> 3) & 3);
#pragma unroll
  for (int i = 0; i < 2; ++i) {
    int row = i * 64 + rlo;
    gload_lds16(g + (size_t)row * KDIM + kt * 32 + c * 8,
                (unsigned short*)(ldsOp + i * 4096 + tid * 16));
  }
}
__device__ __forceinline__ bf16x8 lds_frag32(const char* op, int r, int c16) {
  return *(const bf16x8*)(op + r * 64 + ((c16 ^ ((r >> 1) & 3)) << 4));
}

// ================= 128x128 bf16 MFMA core, BK=32, 3-slot ring, counted vmcnt ==================
// (unchanged — proven at R7/R10)
__device__ __forceinline__ void gemm128_k512(
    const unsigned short* __restrict__ Ag, const unsigned short* __restrict__ Bg,
    char* lds, int tid, f32x4 acc[4][4]) {
  int lane = tid & 63, w = tid >> 6;
  int wr0 = (w >> 1) * 64, wc0 = (w & 1) * 64;
  int c16 = lane >> 4, rl = lane & 15;
  stage32(Ag, lds, tid, 0);
  stage32(Bg, lds + 8192, tid, 0);
  stage32(Ag, lds + 16384, tid, 1);
  stage32(Bg, lds + 16384 + 8192, tid, 1);
#pragma unroll
  for (int s = 0; s < 16; ++s) {
    if (s < 15) asm volatile("s_waitcnt vmcnt(4)\n\ts_barrier" ::: "memory");
    else        asm volatile("s_waitcnt vmcnt(0)\n\ts_barrier" ::: "memory");
    char* cur = lds + (s % 3) * 16384;
    if (s + 2 < 16) {
      char* nxt = lds + ((s + 2) % 3) * 16384;
      stage32(Ag, nxt, tid, s + 2);
      stage32(Bg, nxt + 8192, tid, s + 2);
    }
    bf16x8 av[4], bv[4];
#pragma unroll
    for (int f = 0; f < 4; ++f) {
      av[f] = lds_frag32(cur, wr0 + f * 16 + rl, c16);
      bv[f] = lds_frag32(cur + 8192, wc0 + f * 16 + rl, c16);
    }
    __builtin_amdgcn_s_setprio(1);
#pragma unroll
    for (int fi = 0; fi < 4; ++fi)
#pragma unroll
      for (int fj = 0; fj < 4; ++fj)
        acc[fi][fj] = __builtin_amdgcn_mfma_f32_16x16x32_bf16(av[fi], bv[fj], acc[fi][fj], 0, 0, 0);
    __builtin_amdgcn_s_setprio(0);
  }
}

// ================= merged weight-fuse GEMM ====================================================
struct FuseArgs {
  const unsigned short *wt0, *wt1, *wt2, *wt3;
  unsigned short *wf0, *wf1, *wf2, *wf3;
};
__global__ __launch_bounds__(256, 3) void fuse_all(const unsigned short* __restrict__ Wpb, FuseArgs a) {
  __shared__ __align__(16) char lds[49152];
  int bid = blockIdx.x;
  int e, base, P;
  if (bid < 64)       { e = 0; base = 0;   P = 4; }
  else if (bid < 192) { e = 1; base = 64;  P = 8; }
  else if (bid < 384) { e = 2; base = 192; P = 12; }
  else                { e = 3; base = 384; P = 24; }
  const unsigned short* WtB = e == 0 ? a.wt0 : e == 1 ? a.wt1 : e == 2 ? a.wt2 : a.wt3;
  unsigned short* Wf = e == 0 ? a.wf0 : e == 1 ? a.wf1 : e == 2 ? a.wf2 : a.wf3;
  int r = bid - base;
  int tileM = r % (4 * P), tileN = r / (4 * P);
  int tid = threadIdx.x;
  int lane = tid & 63, w = tid >> 6;
  int wr0 = (w >> 1) * 64, wc0 = (w & 1) * 64;
  int j = (tileM * 128) >> 9;
  const unsigned short* Ag = Wpb + (size_t)((tileM * 128) & 511) * 512;
  const unsigned short* Bg = WtB + (size_t)j * 262144 + (size_t)(tileN * 128) * 512;
  f32x4 acc[4][4] = {};
  gemm128_k512(Ag, Bg, lds, tid, acc);
#pragma unroll
  for (int fi = 0; fi < 4; ++fi)
#pragma unroll
    for (int fj = 0; fj < 4; ++fj) {
      int col = tileN * 128 + wc0 + fj * 16 + (lane & 15);
#pragma unroll
      for (int r2 = 0; r2 < 4; ++r2) {
        int m = tileM * 128 + wr0 + fi * 16 + (lane >> 4) * 4 + r2;
        Wf[(size_t)m * 512 + col] = f2bf(acc[fi][fj][r2]);
      }
    }
}

// ================= fused expert GEMM + gate + scatter (STORE / ADD kernels) ===================
// Routing: E0+E2 disjoint rows -> STORE kernel; E1+E3 disjoint rows -> ADD kernel (pure RMW).
// Stream order gives all deps.  2D XCD chunking <XM,XN>: xcd owns TM/XM x TN/XN tiles ->
// per-XCD operand panels fit the 4MB L2 (E0/E1: 3.6MB, E2/E3: 3.25MB).
// RMW loads happen AFTER the GEMM (batched 16/fi-group, 16 live regs — R14's pre-GEMM
// prefetch of 64 values spilled to scratch: +310MB traffic, 2.2x slower.  Do not repeat.)
// Output stream (RMW loads + stores) uses non-temporal hints: no L2 pollution of panels,
// zero register cost.
template <int L, int P, int EXPERT, int XM, int XN, bool STORE>
__device__ __forceinline__ void expert_body(
    const unsigned short* __restrict__ A, const unsigned short* __restrict__ Wf,
    const float* __restrict__ bf, const float* __restrict__ gates,
    const int* __restrict__ bidx, float* __restrict__ out, char* lds, int bid, int tid) {
  constexpr int TM = L;
  constexpr int TN = 4 * P;
  constexpr int TMl = TM / XM, TNl = TN / XN;  // divisible by construction
  constexpr int EBASE = 128 * EXPERT;
  int xcd = bid & 7, pos = bid >> 3;
  int tileM = (xcd / XN) * TMl + pos / TNl;
  int tileN = (xcd % XN) * TNl + pos % TNl;

  int lane = tid & 63, w = tid >> 6;
  int wr0 = (w >> 1) * 64, wc0 = (w & 1) * 64;
  const unsigned short* Ag = A + (size_t)tileM * 128 * KDIM;
  const unsigned short* Bg = Wf + (size_t)tileN * 128 * KDIM;
  f32x4 acc[4][4] = {};
  gemm128_k512(Ag, Bg, lds, tid, acc);

  int j = tileN >> 2;
  int obase = (tileN & 3) * 128;
  float bv[4];
  int ocol[4];
#pragma unroll
  for (int fj = 0; fj < 4; ++fj) {
    ocol[fj] = obase + wc0 + fj * 16 + (lane & 15);
    bv[fj] = bf[(j << 9) + ocol[fj]];
  }
#pragma unroll
  for (int fi = 0; fi < 4; ++fi) {
    int m0 = tileM * 128 + wr0 + fi * 16 + (lane >> 4) * 4;
    int n = m0 / L, li = m0 - n * L;
    float* rp[4]; float gg[4];
#pragma unroll
    for (int r = 0; r < 4; ++r) {
      if (li == L) { li = 0; ++n; }
      int b = bidx[EBASE + n];
      gg[r] = gates[b * 4 + EXPERT];
      rp[r] = out + ((size_t)b * 336 + li * P + j) * 512;
      ++li;
    }
    float old[4][4];
    if (!STORE) {  // batch 16 RMW nt-loads: one latency exposure, 16 live regs only
#pragma unroll
      for (int r = 0; r < 4; ++r)
#pragma unroll
        for (int fj = 0; fj < 4; ++fj)
          old[r][fj] = __builtin_nontemporal_load(rp[r] + ocol[fj]);
    }
#pragma unroll
    for (int r = 0; r < 4; ++r)
#pragma unroll
      for (int fj = 0; fj < 4; ++fj) {
        float v = gg[r] * (acc[fi][fj][r] + bv[fj]);
        if (!STORE) v += old[r][fj];
        __builtin_nontemporal_store(v, rp[r] + ocol[fj]);
      }
  }
}

struct ScatterArgs {
  const unsigned short *xa, *wa;
  const unsigned short *xb, *wb;
  const float *bfa, *bfb;
  const float *gates;
  const int *bidx;
  float *out;
};

// STORE kernel: E0 (bid<1344) + E2 (bid>=1344) — disjoint output rows, pure stores.
__global__ __launch_bounds__(256, 3) void scatter_store(ScatterArgs a) {
  __shared__ __align__(16) char lds[49152];
  int tid = threadIdx.x;
  if (blockIdx.x < 1344)
    expert_body<84, 4, 0, 4, 2, true>(a.xa, a.wa, a.bfa, a.gates, a.bidx, a.out, lds, blockIdx.x, tid);
  else
    expert_body<28, 12, 2, 2, 4, true>(a.xb, a.wb, a.bfb, a.gates, a.bidx, a.out, lds, blockIdx.x - 1344, tid);
}

// ADD kernel: E1 (bid<1344) + E3 (bid>=1344) — disjoint output rows, pure RMW.
__global__ __launch_bounds__(256, 3) void scatter_add(ScatterArgs a) {
  __shared__ __align__(16) char lds[49152];
  int tid = threadIdx.x;
  if (blockIdx.x < 1344)
    expert_body<42, 8, 1, 2, 4, false>(a.xa, a.wa, a.bfa, a.gates, a.bidx, a.out, lds, blockIdx.x, tid);
  else
    expert_body<14, 24, 3, 1, 8, false>(a.xb, a.wb, a.bfb, a.gates, a.bidx, a.out, lds, blockIdx.x - 1344, tid);
}

extern "C" void kernel_launch(void* const* d_in, const int* in_sizes, int n_in,
                              void* d_out, int out_size, void* d_ws, size_t ws_size,
                              hipStream_t stream) {
  const float* xs[4]   = {(const float*)d_in[0], (const float*)d_in[3], (const float*)d_in[6], (const float*)d_in[9]};
  const float* Wfp[4]  = {(const float*)d_in[1], (const float*)d_in[4], (const float*)d_in[7], (const float*)d_in[10]};
  const float* bias[4] = {(const float*)d_in[2], (const float*)d_in[5], (const float*)d_in[8], (const float*)d_in[11]};
  const float* gates = (const float*)d_in[12];
  const float* Wp    = (const float*)d_in[13];
  const float* bp    = (const float*)d_in[14];
  const int* bidx    = (const int*)d_in[15];

  static const int xs_elems[4] = {5505024, 2752512, 1835008, 917504};
  static const int W_elems[4]  = {1048576, 2097152, 3145728, 6291456};

  unsigned short* w = (unsigned short*)d_ws;
  size_t off = 0;
  unsigned short* xsb[4]; unsigned short* WtB[4]; unsigned short* Wfb[4];
  for (int i = 0; i < 4; i++) { xsb[i] = w + off; off += xs_elems[i]; }
  for (int i = 0; i < 4; i++) { WtB[i] = w + off; off += W_elems[i]; }
  for (int i = 0; i < 4; i++) { Wfb[i] = w + off; off += W_elems[i]; }
  unsigned short* Wpb = w + off; off += 262144;
  float* bfused = (float*)(w + off);  // 48*512 floats

  // --- prep: ONE launch (bias | transpose | cvt) ---
  PrepArgs pa;
  pa.s0 = xs[0]; pa.s1 = xs[1]; pa.s2 = xs[2]; pa.s3 = xs[3]; pa.s4 = Wp;
  pa.d0 = xsb[0]; pa.d1 = xsb[1]; pa.d2 = xsb[2]; pa.d3 = xsb[3]; pa.d4 = Wpb;
  pa.w0 = Wfp[0]; pa.w1 = Wfp[1]; pa.w2 = Wfp[2]; pa.w3 = Wfp[3];
  pa.t0 = WtB[0]; pa.t1 = WtB[1]; pa.t2 = WtB[2]; pa.t3 = WtB[3];
  pa.b0 = bias[0]; pa.b1 = bias[1]; pa.b2 = bias[2]; pa.b3 = bias[3];
  pa.Wp = Wp; pa.bp = bp; pa.bf = bfused;
  prep_all<<<8624, 256, 0, stream>>>(pa);

  // --- weight fuse GEMM ---
  FuseArgs fa = {WtB[0], WtB[1], WtB[2], WtB[3], Wfb[0], Wfb[1], Wfb[2], Wfb[3]};
  fuse_all<<<768, 256, 0, stream>>>(Wpb, fa);

  // --- expert GEMM + gated scatter: STORE (E0+E2) then ADD (E1+E3) ---
  ScatterArgs sa;
  sa.gates = gates; sa.bidx = bidx; sa.out = (float*)d_out;
  sa.xa = xsb[0]; sa.wa = Wfb[0]; sa.bfa = bfused + 0 * 512;
  sa.xb = xsb[2]; sa.wb = Wfb[2]; sa.bfb = bfused + 12 * 512;
  scatter_store<<<2688, 256, 0, stream>>>(sa);

  sa.xa = xsb[1]; sa.wa = Wfb[1]; sa.bfa = bfused + 4 * 512;
  sa.xb = xsb[3]; sa.wb = Wfb[3]; sa.bfb = bfused + 24 * 512;
  scatter_add<<<2688, 256, 0, stream>>>(sa);
}

// Round 16
// 211.997 us; speedup vs baseline: 1.7145x; 1.1856x over previous
//
#include <hip/hip_runtime.h>
#include <stdint.h>

typedef __bf16 bf16_t;
typedef bf16_t bf16x8 __attribute__((ext_vector_type(8)));
typedef float f32x4 __attribute__((ext_vector_type(4)));
typedef unsigned short u16x8 __attribute__((ext_vector_type(8)));

#define KDIM 512

__device__ __forceinline__ unsigned short f2bf(float f) {
  unsigned int u = __float_as_uint(f);
  u = (u + 0x7FFFu + ((u >> 16) & 1u)) >> 16;
  return (unsigned short)u;
}

// ================= merged prep: bias | transpose+cvt | fp32->bf16 cvt =========================
// grid 8624: [0,48) bias fuse; [48,3120) transpose W -> WtB; [3120,8624) cvt xs+Wp.
struct PrepArgs {
  const float *s0, *s1, *s2, *s3, *s4;
  unsigned short *d0, *d1, *d2, *d3, *d4;
  const float *w0, *w1, *w2, *w3;
  unsigned short *t0, *t1, *t2, *t3;
  const float *b0, *b1, *b2, *b3;
  const float *Wp, *bp;
  float *bf;
};
__device__ __forceinline__ void cvt8(const float* s, unsigned short* d, int i) {
  const float4* sp = (const float4*)s;
  float4 a = sp[2 * (size_t)i], b = sp[2 * (size_t)i + 1];
  u16x8 r;
  r[0] = f2bf(a.x); r[1] = f2bf(a.y); r[2] = f2bf(a.z); r[3] = f2bf(a.w);
  r[4] = f2bf(b.x); r[5] = f2bf(b.y); r[6] = f2bf(b.z); r[7] = f2bf(b.w);
  *(u16x8*)(d + (size_t)8 * i) = r;
}
__global__ __launch_bounds__(256) void prep_all(PrepArgs a) {
  __shared__ float tile[64][65];
  int bid = blockIdx.x;
  int t = threadIdx.x;
  if (bid < 48) {  // ---- bias fuse (float4 loads, 4-wide acc) ----
    int jg = bid;
    int e, base;
    if (jg < 4)       { e = 0; base = 0; }
    else if (jg < 12) { e = 1; base = 4; }
    else if (jg < 24) { e = 2; base = 12; }
    else              { e = 3; base = 24; }
    const float* b = e == 0 ? a.b0 : e == 1 ? a.b1 : e == 2 ? a.b2 : a.b3;
    int jl = jg - base;
    const float4* br4 = (const float4*)(b + (size_t)jl * 512);
#pragma unroll
    for (int oo = 0; oo < 2; ++oo) {
      int o = t + oo * 256;
      const float4* wr4 = (const float4*)(a.Wp + (size_t)o * 512);
      float sx = 0.f, sy = 0.f, sz = 0.f, sw = 0.f;
#pragma unroll 4
      for (int i = 0; i < 128; ++i) {
        float4 wv = wr4[i], bv = br4[i];
        sx += wv.x * bv.x; sy += wv.y * bv.y; sz += wv.z * bv.z; sw += wv.w * bv.w;
      }
      a.bf[(size_t)jg * 512 + o] = a.bp[o] + ((sx + sy) + (sz + sw));
    }
  } else if (bid < 3120) {  // ---- transpose+cvt: float4 loads, ushort8 stores ----
    int r = bid - 48;
    int e, base, P;
    if (r < 256)       { e = 0; base = 0;    P = 4; }
    else if (r < 768)  { e = 1; base = 256;  P = 8; }
    else if (r < 1536) { e = 2; base = 768;  P = 12; }
    else               { e = 3; base = 1536; P = 24; }
    const float* W = e == 0 ? a.w0 : e == 1 ? a.w1 : e == 2 ? a.w2 : a.w3;
    unsigned short* Wt = e == 0 ? a.t0 : e == 1 ? a.t1 : e == 2 ? a.t2 : a.t3;
    r -= base;
    int qb = r % (P * 8), db = r / (P * 8);
    int q0 = qb * 64, d0 = db * 64;
    int c4 = t & 15, rgrp = t >> 4;
#pragma unroll
    for (int i = 0; i < 4; ++i) {
      int row = rgrp + i * 16;
      float4 v = *(const float4*)&W[(size_t)(q0 + row) * 512 + d0 + c4 * 4];
      tile[row][c4 * 4 + 0] = v.x; tile[row][c4 * 4 + 1] = v.y;
      tile[row][c4 * 4 + 2] = v.z; tile[row][c4 * 4 + 3] = v.w;
    }
    __syncthreads();
    int j = q0 >> 9, e0 = q0 & 511;
    size_t obase = (size_t)j * 262144 + (size_t)d0 * 512 + e0;
#pragma unroll
    for (int it = 0; it < 2; ++it) {
      int pair = it * 256 + t;
      int dd = pair >> 3, ch = pair & 7;
      u16x8 o8;
#pragma unroll
      for (int k = 0; k < 8; ++k) o8[k] = f2bf(tile[ch * 8 + k][dd]);
      *(u16x8*)&Wt[obase + (size_t)dd * 512 + ch * 8] = o8;
    }
  } else {  // ---- fp32->bf16 cvt ----
    int i = (bid - 3120) * 256 + t;
    if (i < 688128)       cvt8(a.s0, a.d0, i);
    else if (i < 1032192) cvt8(a.s1, a.d1, i - 688128);
    else if (i < 1261568) cvt8(a.s2, a.d2, i - 1032192);
    else if (i < 1376256) cvt8(a.s3, a.d3, i - 1261568);
    else                  cvt8(a.s4, a.d4, i - 1376256);
  }
}

// ================= async global->LDS helpers ==================================================
__device__ __forceinline__ void gload_lds16(const unsigned short* g, unsigned short* l) {
  __builtin_amdgcn_global_load_lds(
      (const __attribute__((address_space(1))) void*)g,
      (__attribute__((address_space(3))) void*)l, 16, 0, 0);
}

// ---- stage a 128x32 bf16 tile (8 KB): LDS dest linear, global source chunk-swizzled ----
__device__ __forceinline__ void stage32(const unsigned short* __restrict__ g,
                                        char* ldsOp, int tid, int kt) {
  int rlo = tid >> 2;
  int c = (tid & 3) ^ ((tid >> 3) & 3);
#pragma unroll
  for (int i = 0; i < 2; ++i) {
    int row = i * 64 + rlo;
    gload_lds16(g + (size_t)row * KDIM + kt * 32 + c * 8,
                (unsigned short*)(ldsOp + i * 4096 + tid * 16));
  }
}
__device__ __forceinline__ bf16x8 lds_frag32(const char* op, int r, int c16) {
  return *(const bf16x8*)(op + r * 64 + ((c16 ^ ((r >> 1) & 3)) << 4));
}

// ================= 128x128 bf16 MFMA core, BK=32, 3-slot ring, counted vmcnt ==================
// (unchanged — proven at R7/R10)
__device__ __forceinline__ void gemm128_k512(
    const unsigned short* __restrict__ Ag, const unsigned short* __restrict__ Bg,
    char* lds, int tid, f32x4 acc[4][4]) {
  int lane = tid & 63, w = tid >> 6;
  int wr0 = (w >> 1) * 64, wc0 = (w & 1) * 64;
  int c16 = lane >> 4, rl = lane & 15;
  stage32(Ag, lds, tid, 0);
  stage32(Bg, lds + 8192, tid, 0);
  stage32(Ag, lds + 16384, tid, 1);
  stage32(Bg, lds + 16384 + 8192, tid, 1);
#pragma unroll
  for (int s = 0; s < 16; ++s) {
    if (s < 15) asm volatile("s_waitcnt vmcnt(4)\n\ts_barrier" ::: "memory");
    else        asm volatile("s_waitcnt vmcnt(0)\n\ts_barrier" ::: "memory");
    char* cur = lds + (s % 3) * 16384;
    if (s + 2 < 16) {
      char* nxt = lds + ((s + 2) % 3) * 16384;
      stage32(Ag, nxt, tid, s + 2);
      stage32(Bg, nxt + 8192, tid, s + 2);
    }
    bf16x8 av[4], bv[4];
#pragma unroll
    for (int f = 0; f < 4; ++f) {
      av[f] = lds_frag32(cur, wr0 + f * 16 + rl, c16);
      bv[f] = lds_frag32(cur + 8192, wc0 + f * 16 + rl, c16);
    }
    __builtin_amdgcn_s_setprio(1);
#pragma unroll
    for (int fi = 0; fi < 4; ++fi)
#pragma unroll
      for (int fj = 0; fj < 4; ++fj)
        acc[fi][fj] = __builtin_amdgcn_mfma_f32_16x16x32_bf16(av[fi], bv[fj], acc[fi][fj], 0, 0, 0);
    __builtin_amdgcn_s_setprio(0);
  }
}

// ================= merged weight-fuse GEMM ====================================================
struct FuseArgs {
  const unsigned short *wt0, *wt1, *wt2, *wt3;
  unsigned short *wf0, *wf1, *wf2, *wf3;
};
__global__ __launch_bounds__(256, 3) void fuse_all(const unsigned short* __restrict__ Wpb, FuseArgs a) {
  __shared__ __align__(16) char lds[49152];
  int bid = blockIdx.x;
  int e, base, P;
  if (bid < 64)       { e = 0; base = 0;   P = 4; }
  else if (bid < 192) { e = 1; base = 64;  P = 8; }
  else if (bid < 384) { e = 2; base = 192; P = 12; }
  else                { e = 3; base = 384; P = 24; }
  const unsigned short* WtB = e == 0 ? a.wt0 : e == 1 ? a.wt1 : e == 2 ? a.wt2 : a.wt3;
  unsigned short* Wf = e == 0 ? a.wf0 : e == 1 ? a.wf1 : e == 2 ? a.wf2 : a.wf3;
  int r = bid - base;
  int tileM = r % (4 * P), tileN = r / (4 * P);
  int tid = threadIdx.x;
  int lane = tid & 63, w = tid >> 6;
  int wr0 = (w >> 1) * 64, wc0 = (w & 1) * 64;
  int j = (tileM * 128) >> 9;
  const unsigned short* Ag = Wpb + (size_t)((tileM * 128) & 511) * 512;
  const unsigned short* Bg = WtB + (size_t)j * 262144 + (size_t)(tileN * 128) * 512;
  f32x4 acc[4][4] = {};
  gemm128_k512(Ag, Bg, lds, tid, acc);
#pragma unroll
  for (int fi = 0; fi < 4; ++fi)
#pragma unroll
    for (int fj = 0; fj < 4; ++fj) {
      int col = tileN * 128 + wc0 + fj * 16 + (lane & 15);
#pragma unroll
      for (int r2 = 0; r2 < 4; ++r2) {
        int m = tileM * 128 + wr0 + fi * 16 + (lane >> 4) * 4 + r2;
        Wf[(size_t)m * 512 + col] = f2bf(acc[fi][fj][r2]);
      }
    }
}

// ================= fused expert GEMM + gate + scatter (STORE / ADD kernels) ===================
// Routing: E0+E2 disjoint rows -> STORE kernel; E1+E3 disjoint rows -> ADD kernel (pure RMW).
// Stream order gives all deps.  2D XCD chunking <XM,XN>: xcd owns TM/XM x TN/XN tiles ->
// per-XCD operand panels fit the 4MB L2 (verified: FETCH 154->115 MB, R15).
// RMW loads AFTER the GEMM, batched 16/fi-group (R14's 64-value pre-GEMM prefetch spilled:
// +310MB scratch traffic, 2.2x slower).  PLAIN loads/stores — R15's non-temporal hints
// bypassed L3 and turned the RMW loads (L3-hits on the just-written output) into full-HBM
// latency: 110->129us.  Do not reintroduce either.
template <int L, int P, int EXPERT, int XM, int XN, bool STORE>
__device__ __forceinline__ void expert_body(
    const unsigned short* __restrict__ A, const unsigned short* __restrict__ Wf,
    const float* __restrict__ bf, const float* __restrict__ gates,
    const int* __restrict__ bidx, float* __restrict__ out, char* lds, int bid, int tid) {
  constexpr int TM = L;
  constexpr int TN = 4 * P;
  constexpr int TMl = TM / XM, TNl = TN / XN;  // divisible by construction
  constexpr int EBASE = 128 * EXPERT;
  int xcd = bid & 7, pos = bid >> 3;
  int tileM = (xcd / XN) * TMl + pos / TNl;
  int tileN = (xcd % XN) * TNl + pos % TNl;

  int lane = tid & 63, w = tid >> 6;
  int wr0 = (w >> 1) * 64, wc0 = (w & 1) * 64;
  const unsigned short* Ag = A + (size_t)tileM * 128 * KDIM;
  const unsigned short* Bg = Wf + (size_t)tileN * 128 * KDIM;
  f32x4 acc[4][4] = {};
  gemm128_k512(Ag, Bg, lds, tid, acc);

  int j = tileN >> 2;
  int obase = (tileN & 3) * 128;
  float bv[4];
  int ocol[4];
#pragma unroll
  for (int fj = 0; fj < 4; ++fj) {
    ocol[fj] = obase + wc0 + fj * 16 + (lane & 15);
    bv[fj] = bf[(j << 9) + ocol[fj]];
  }
#pragma unroll
  for (int fi = 0; fi < 4; ++fi) {
    int m0 = tileM * 128 + wr0 + fi * 16 + (lane >> 4) * 4;
    int n = m0 / L, li = m0 - n * L;
    float* rp[4]; float gg[4];
#pragma unroll
    for (int r = 0; r < 4; ++r) {
      if (li == L) { li = 0; ++n; }
      int b = bidx[EBASE + n];
      gg[r] = gates[b * 4 + EXPERT];
      rp[r] = out + ((size_t)b * 336 + li * P + j) * 512;
      ++li;
    }
    float old[4][4];
    if (!STORE) {  // batch 16 RMW loads: one latency exposure, 16 live regs only
#pragma unroll
      for (int r = 0; r < 4; ++r)
#pragma unroll
        for (int fj = 0; fj < 4; ++fj)
          old[r][fj] = rp[r][ocol[fj]];
    }
#pragma unroll
    for (int r = 0; r < 4; ++r)
#pragma unroll
      for (int fj = 0; fj < 4; ++fj) {
        float v = gg[r] * (acc[fi][fj][r] + bv[fj]);
        if (!STORE) v += old[r][fj];
        rp[r][ocol[fj]] = v;
      }
  }
}

struct ScatterArgs {
  const unsigned short *xa, *wa;
  const unsigned short *xb, *wb;
  const float *bfa, *bfb;
  const float *gates;
  const int *bidx;
  float *out;
};

// STORE kernel: E0 (bid<1344) + E2 (bid>=1344) — disjoint output rows, pure stores.
__global__ __launch_bounds__(256, 3) void scatter_store(ScatterArgs a) {
  __shared__ __align__(16) char lds[49152];
  int tid = threadIdx.x;
  if (blockIdx.x < 1344)
    expert_body<84, 4, 0, 4, 2, true>(a.xa, a.wa, a.bfa, a.gates, a.bidx, a.out, lds, blockIdx.x, tid);
  else
    expert_body<28, 12, 2, 2, 4, true>(a.xb, a.wb, a.bfb, a.gates, a.bidx, a.out, lds, blockIdx.x - 1344, tid);
}

// ADD kernel: E1 (bid<1344) + E3 (bid>=1344) — disjoint output rows, pure RMW.
__global__ __launch_bounds__(256, 3) void scatter_add(ScatterArgs a) {
  __shared__ __align__(16) char lds[49152];
  int tid = threadIdx.x;
  if (blockIdx.x < 1344)
    expert_body<42, 8, 1, 2, 4, false>(a.xa, a.wa, a.bfa, a.gates, a.bidx, a.out, lds, blockIdx.x, tid);
  else
    expert_body<14, 24, 3, 1, 8, false>(a.xb, a.wb, a.bfb, a.gates, a.bidx, a.out, lds, blockIdx.x - 1344, tid);
}

extern "C" void kernel_launch(void* const* d_in, const int* in_sizes, int n_in,
                              void* d_out, int out_size, void* d_ws, size_t ws_size,
                              hipStream_t stream) {
  const float* xs[4]   = {(const float*)d_in[0], (const float*)d_in[3], (const float*)d_in[6], (const float*)d_in[9]};
  const float* Wfp[4]  = {(const float*)d_in[1], (const float*)d_in[4], (const float*)d_in[7], (const float*)d_in[10]};
  const float* bias[4] = {(const float*)d_in[2], (const float*)d_in[5], (const float*)d_in[8], (const float*)d_in[11]};
  const float* gates = (const float*)d_in[12];
  const float* Wp    = (const float*)d_in[13];
  const float* bp    = (const float*)d_in[14];
  const int* bidx    = (const int*)d_in[15];

  static const int xs_elems[4] = {5505024, 2752512, 1835008, 917504};
  static const int W_elems[4]  = {1048576, 2097152, 3145728, 6291456};

  unsigned short* w = (unsigned short*)d_ws;
  size_t off = 0;
  unsigned short* xsb[4]; unsigned short* WtB[4]; unsigned short* Wfb[4];
  for (int i = 0; i < 4; i++) { xsb[i] = w + off; off += xs_elems[i]; }
  for (int i = 0; i < 4; i++) { WtB[i] = w + off; off += W_elems[i]; }
  for (int i = 0; i < 4; i++) { Wfb[i] = w + off; off += W_elems[i]; }
  unsigned short* Wpb = w + off; off += 262144;
  float* bfused = (float*)(w + off);  // 48*512 floats

  // --- prep: ONE launch (bias | transpose | cvt) ---
  PrepArgs pa;
  pa.s0 = xs[0]; pa.s1 = xs[1]; pa.s2 = xs[2]; pa.s3 = xs[3]; pa.s4 = Wp;
  pa.d0 = xsb[0]; pa.d1 = xsb[1]; pa.d2 = xsb[2]; pa.d3 = xsb[3]; pa.d4 = Wpb;
  pa.w0 = Wfp[0]; pa.w1 = Wfp[1]; pa.w2 = Wfp[2]; pa.w3 = Wfp[3];
  pa.t0 = WtB[0]; pa.t1 = WtB[1]; pa.t2 = WtB[2]; pa.t3 = WtB[3];
  pa.b0 = bias[0]; pa.b1 = bias[1]; pa.b2 = bias[2]; pa.b3 = bias[3];
  pa.Wp = Wp; pa.bp = bp; pa.bf = bfused;
  prep_all<<<8624, 256, 0, stream>>>(pa);

  // --- weight fuse GEMM ---
  FuseArgs fa = {WtB[0], WtB[1], WtB[2], WtB[3], Wfb[0], Wfb[1], Wfb[2], Wfb[3]};
  fuse_all<<<768, 256, 0, stream>>>(Wpb, fa);

  // --- expert GEMM + gated scatter: STORE (E0+E2) then ADD (E1+E3) ---
  ScatterArgs sa;
  sa.gates = gates; sa.bidx = bidx; sa.out = (float*)d_out;
  sa.xa = xsb[0]; sa.wa = Wfb[0]; sa.bfa = bfused + 0 * 512;
  sa.xb = xsb[2]; sa.wb = Wfb[2]; sa.bfb = bfused + 12 * 512;
  scatter_store<<<2688, 256, 0, stream>>>(sa);

  sa.xa = xsb[1]; sa.wa = Wfb[1]; sa.bfa = bfused + 4 * 512;
  sa.xb = xsb[3]; sa.wb = Wfb[3]; sa.bfb = bfused + 24 * 512;
  scatter_add<<<2688, 256, 0, stream>>>(sa);
}